// Round 4
// baseline (58.127 us; speedup 1.0000x reference)
//
#include <hip/hip_runtime.h>

#define UNITS 256
#define BATCH 256

typedef float fx4 __attribute__((ext_vector_type(4)));

// Kernel 1: pure zeroing of out[256][256] (atomic flush target).
// 64 blocks x 256 threads x float4 = 256KB, <1us.
__global__ __launch_bounds__(256) void k_zero(float* __restrict__ out) {
    const int i = (blockIdx.x * 256 + threadIdx.x) << 2;
    *reinterpret_cast<fx4*>(out + i) = fx4{0.f, 0.f, 0.f, 0.f};
}

// Kernel 2: chunked accumulation, block-uniform segment walk.
// - Per-block redundant LDS scan of sizes (removes serial k_prep scan from the
//   inter-kernel critical path; nclasses/nfeature are 1KB each, L2-hot).
// - Balanced two-tier chunking: exactly 2048 blocks, nE4 blocks get lo+4 rows,
//   rest get lo rows -> no straggler round (vs 2000 equal chunks).
// - Wave rl handles rows r0+rl, +4, ...; lane owns a float4 column slice
//   (wave = contiguous 1KB row read). Nontemporal: single-use stream > L3.
// - Steady loop unrolled x8 = 8 outstanding 16B loads/lane.
// - Cross-wave LDS reduce; wave 0 issues one scaled atomic flush per
//   block-segment (divide folded in).
__global__ __launch_bounds__(256) void k_accum(const float* __restrict__ x,
                                               const int* __restrict__ nclasses,
                                               const int* __restrict__ nfeature,
                                               float* __restrict__ out,
                                               int total_rows, int lo, int nE4) {
    __shared__ int   s_ends[BATCH];
    __shared__ float s_inv[BATCH];
    __shared__ fx4   s_red[3][64];
    const int t  = threadIdx.x;
    const int ln = t & 63;
    const int rl = t >> 6;

    {
        const int sz = nclasses[t] * nfeature[t];
        s_inv[t]  = 1.0f / (float)sz;
        s_ends[t] = sz;
    }
    __syncthreads();
    #pragma unroll
    for (int off = 1; off < BATCH; off <<= 1) {   // Hillis-Steele inclusive scan
        int v   = s_ends[t];
        int add = (t >= off) ? s_ends[t - off] : 0;
        __syncthreads();
        s_ends[t] = v + add;
        __syncthreads();
    }

    // balanced chunk geometry
    const int b    = blockIdx.x;
    const int hi   = lo + 4;
    const int r0   = (b < nE4) ? b * hi : nE4 * hi + (b - nE4) * lo;
    const int sz   = (b < nE4) ? hi : lo;
    const int rend = min(r0 + sz, total_rows);
    if (r0 >= rend) return;               // block-uniform (only tiny-T edge)

    // block-uniform binary search: first segment with end > r0
    int slo = 0, shi = BATCH;
    while (slo < shi) {
        int mid = (slo + shi) >> 1;
        if (s_ends[mid] > r0) shi = mid; else slo = mid + 1;
    }
    int seg = slo;

    const int c = ln << 2;                // column start (0,4,...,252)
    int r = r0 + rl;                      // per-wave row cursor
    const float* p = x + (size_t)r * UNITS + c;

    for (;;) {
        const int stop = min(s_ends[seg], rend);
        int cnt = (stop - r + 3) >> 2;    // this wave's rows in [r, stop)
        if (cnt < 0) cnt = 0;
        r += cnt << 2;

        fx4 acc = {0.f, 0.f, 0.f, 0.f};
        int k = 0;
        for (; k + 8 <= cnt; k += 8) {    // 8 outstanding 16B loads/lane
            fx4 v0 = __builtin_nontemporal_load((const fx4*)(p));
            fx4 v1 = __builtin_nontemporal_load((const fx4*)(p + 4  * UNITS));
            fx4 v2 = __builtin_nontemporal_load((const fx4*)(p + 8  * UNITS));
            fx4 v3 = __builtin_nontemporal_load((const fx4*)(p + 12 * UNITS));
            fx4 v4 = __builtin_nontemporal_load((const fx4*)(p + 16 * UNITS));
            fx4 v5 = __builtin_nontemporal_load((const fx4*)(p + 20 * UNITS));
            fx4 v6 = __builtin_nontemporal_load((const fx4*)(p + 24 * UNITS));
            fx4 v7 = __builtin_nontemporal_load((const fx4*)(p + 28 * UNITS));
            p += 32 * UNITS;
            acc += ((v0 + v1) + (v2 + v3)) + ((v4 + v5) + (v6 + v7));
        }
        for (; k < cnt; ++k) {
            fx4 v = __builtin_nontemporal_load((const fx4*)(p));
            p += 4 * UNITS;
            acc += v;
        }

        // cross-wave reduce: waves 1-3 -> LDS, wave 0 flushes once
        if (rl) s_red[rl - 1][ln] = acc;
        __syncthreads();
        if (rl == 0) {
            acc += s_red[0][ln];
            acc += s_red[1][ln];
            acc += s_red[2][ln];
            const float s = s_inv[seg];
            float* o = out + seg * UNITS + c;
            unsafeAtomicAdd(o + 0, acc.x * s);
            unsafeAtomicAdd(o + 1, acc.y * s);
            unsafeAtomicAdd(o + 2, acc.z * s);
            unsafeAtomicAdd(o + 3, acc.w * s);
        }
        if (s_ends[seg] >= rend) break;   // last intersecting segment: uniform
        ++seg;
        __syncthreads();                  // protect s_red reuse
    }
}

extern "C" void kernel_launch(void* const* d_in, const int* in_sizes, int n_in,
                              void* d_out, int out_size, void* d_ws, size_t ws_size,
                              hipStream_t stream) {
    const float* x        = (const float*)d_in[0];
    const int*   nclasses = (const int*)d_in[1];
    const int*   nfeature = (const int*)d_in[2];
    float*       out      = (float*)d_out;

    const int total_rows = in_sizes[0] / UNITS;

    // balanced two-tier chunking over exactly 2048 blocks
    const int q   = total_rows >> 11;         // total/2048
    const int lo  = q & ~3;                   // lower chunk, multiple of 4
    const int E   = total_rows - (lo << 11);  // leftover rows
    const int nE4 = (E + 3) >> 2;             // blocks that take lo+4 rows

    k_zero<<<64, 256, 0, stream>>>(out);
    k_accum<<<2048, 256, 0, stream>>>(x, nclasses, nfeature, out,
                                      total_rows, lo, nE4);
}

// Round 5
// 53.817 us; speedup vs baseline: 1.0801x; 1.0801x over previous
//
#include <hip/hip_runtime.h>

#define UNITS 256
#define BATCH 256

typedef float fx4 __attribute__((ext_vector_type(4)));

// Kernel 1: pure zeroing of out[256][256] (atomic flush target). 256KB.
__global__ __launch_bounds__(256) void k_zero(float* __restrict__ out) {
    const int i = (blockIdx.x * 256 + threadIdx.x) << 2;
    *reinterpret_cast<fx4*>(out + i) = fx4{0.f, 0.f, 0.f, 0.f};
}

// Kernel 2: chunked accumulation, block-uniform segment walk.
// - Fast in-block scan of segment sizes: per-wave __shfl_up inclusive scan
//   (6 steps) + cross-wave offsets via LDS -> 2 barriers total (was 16).
// - Balanced two-tier chunking over exactly 2048 blocks (no straggler round).
// - Wave rl handles rows r0+rl, +4, ...; lane owns a float4 column slice
//   (wave = one contiguous 1KB row read per instr). Plain loads (nt hurt).
// - Steady loop unrolled x4 (4 outstanding 16B loads/lane; deeper unroll
//   crosses the 64-VGPR occupancy step for no BW gain).
// - Flush: all 4 waves write partials to LDS; each of 256 threads sums 4
//   partials for ONE column and issues ONE scaled atomic (divide folded in).
__global__ __launch_bounds__(256) void k_accum(const float* __restrict__ x,
                                               const int* __restrict__ nclasses,
                                               const int* __restrict__ nfeature,
                                               float* __restrict__ out,
                                               int total_rows, int lo, int nE4) {
    __shared__ int   s_ends[BATCH];
    __shared__ float s_inv[BATCH];
    __shared__ int   s_wsum[4];
    __shared__ float s_red[4][64][4];
    const int t  = threadIdx.x;
    const int ln = t & 63;
    const int rl = t >> 6;

    // ---- 2-barrier inclusive scan of sizes -> s_ends ----
    {
        const int sz = nclasses[t] * nfeature[t];
        s_inv[t] = 1.0f / (float)sz;
        int v = sz;
        #pragma unroll
        for (int off = 1; off < 64; off <<= 1) {
            int u = __shfl_up(v, off, 64);
            if (ln >= off) v += u;
        }
        if (ln == 63) s_wsum[rl] = v;
        __syncthreads();
        int base = 0;
        #pragma unroll
        for (int w = 0; w < 3; ++w)
            if (w < rl) base += s_wsum[w];
        s_ends[t] = v + base;
        __syncthreads();
    }

    // ---- balanced chunk geometry ----
    const int b    = blockIdx.x;
    const int hi   = lo + 4;
    const int r0   = (b < nE4) ? b * hi : nE4 * hi + (b - nE4) * lo;
    const int csz  = (b < nE4) ? hi : lo;
    const int rend = min(r0 + csz, total_rows);
    if (r0 >= rend) return;               // block-uniform

    // block-uniform binary search: first segment with end > r0
    int slo = 0, shi = BATCH;
    while (slo < shi) {
        int mid = (slo + shi) >> 1;
        if (s_ends[mid] > r0) shi = mid; else slo = mid + 1;
    }
    int seg = slo;

    const int c = ln << 2;                // column start (0,4,...,252)
    int r = r0 + rl;                      // per-wave row cursor
    const float* p = x + (size_t)r * UNITS + c;
    fx4 acc = {0.f, 0.f, 0.f, 0.f};

    for (;;) {
        const int stop = min(s_ends[seg], rend);
        int cnt = (stop - r + 3) >> 2;    // this wave's rows in [r, stop)
        if (cnt < 0) cnt = 0;
        r += cnt << 2;

        int k = 0;
        for (; k + 4 <= cnt; k += 4) {    // 4 outstanding 16B loads/lane
            fx4 v0 = *(const fx4*)(p);
            fx4 v1 = *(const fx4*)(p + 4  * UNITS);
            fx4 v2 = *(const fx4*)(p + 8  * UNITS);
            fx4 v3 = *(const fx4*)(p + 12 * UNITS);
            p += 16 * UNITS;
            acc += (v0 + v1) + (v2 + v3);
        }
        for (; k < cnt; ++k) {
            fx4 v = *(const fx4*)(p);
            p += 4 * UNITS;
            acc += v;
        }

        // ---- flush: 4-wave LDS reduce, 1 atomic per thread ----
        *reinterpret_cast<fx4*>(&s_red[rl][ln][0]) = acc;
        __syncthreads();
        {
            const int q  = t >> 2, e = t & 3;
            const float vsum = s_red[0][q][e] + s_red[1][q][e]
                             + s_red[2][q][e] + s_red[3][q][e];
            unsafeAtomicAdd(out + seg * UNITS + t, vsum * s_inv[seg]);
        }
        if (s_ends[seg] >= rend) break;   // last intersecting segment: uniform
        ++seg;
        acc = fx4{0.f, 0.f, 0.f, 0.f};
        __syncthreads();                  // protect s_red reuse
    }
}

extern "C" void kernel_launch(void* const* d_in, const int* in_sizes, int n_in,
                              void* d_out, int out_size, void* d_ws, size_t ws_size,
                              hipStream_t stream) {
    const float* x        = (const float*)d_in[0];
    const int*   nclasses = (const int*)d_in[1];
    const int*   nfeature = (const int*)d_in[2];
    float*       out      = (float*)d_out;

    const int total_rows = in_sizes[0] / UNITS;

    // balanced two-tier chunking over exactly 2048 blocks
    const int q   = total_rows >> 11;         // total/2048
    const int lo  = q & ~3;                   // lower chunk, multiple of 4
    const int E   = total_rows - (lo << 11);  // leftover rows
    const int nE4 = (E + 3) >> 2;             // blocks that take lo+4 rows

    k_zero<<<64, 256, 0, stream>>>(out);
    k_accum<<<2048, 256, 0, stream>>>(x, nclasses, nfeature, out,
                                      total_rows, lo, nE4);
}